// Round 3
// baseline (136.248 us; speedup 1.0000x reference)
//
#include <hip/hip_runtime.h>

#define K 11
#define RAD 5
#define TILE 64             // 64x64 output tile per block
#define RROWS (TILE + 2*RAD)        // 74 raw rows
#define RSTRIDE 82                  // words/row; ==2 mod 8 -> 4-row lane groups hit disjoint bank quartets
#define RCHUNKS 41                  // float2 chunks per row
#define BSIZE 256
#define IMG_H 512
#define IMG_W 512
#define BATCH 64

__global__ __launch_bounds__(BSIZE, 3) void ssim_fused_kernel(
    const float* __restrict__ img1, const float* __restrict__ img2,
    const float* __restrict__ window, float* __restrict__ partials)
{
    __shared__ float sA[RROWS * RSTRIDE];
    __shared__ float sB[RROWS * RSTRIDE];
    __shared__ float gwS[K];
    __shared__ float wred[4];

    const int tid = threadIdx.x;
    const int b   = blockIdx.z;
    const int ty0 = blockIdx.y * TILE;
    const int tx0 = blockIdx.x * TILE;

    // 1-D gaussian from row sums of the 2-D window (rows sum to g[i] since sum(g)=1)
    if (tid < K) {
        float s = 0.f;
        #pragma unroll
        for (int j = 0; j < K; ++j) s += window[tid*K + j];
        gwS[tid] = s;
    }

    const float* p1 = img1 + (size_t)b * (IMG_H*IMG_W);
    const float* p2 = img2 + (size_t)b * (IMG_H*IMG_W);

    // stage raw tiles (zero-filled halo = SAME zero padding), float2 chunks
    for (int idx = tid; idx < RROWS * RCHUNKS; idx += BSIZE) {
        int r = idx / RCHUNKS;
        int q = idx - r * RCHUNKS;
        int gr = ty0 - RAD + r;
        int gc = tx0 - 8 + 2*q;
        float2 va = {0.f, 0.f}, vb = {0.f, 0.f};
        if (gr >= 0 && gr < IMG_H) {
            if (gc >= 0 && gc + 1 < IMG_W) {
                va = *(const float2*)(p1 + (size_t)gr*IMG_W + gc);
                vb = *(const float2*)(p2 + (size_t)gr*IMG_W + gc);
            } else {
                float* pa = (float*)&va; float* pb = (float*)&vb;
                #pragma unroll
                for (int e = 0; e < 2; ++e) {
                    int c = gc + e;
                    if (c >= 0 && c < IMG_W) {
                        pa[e] = p1[(size_t)gr*IMG_W + c];
                        pb[e] = p2[(size_t)gr*IMG_W + c];
                    }
                }
            }
        }
        *(float2*)&sA[r*RSTRIDE + 2*q] = va;   // 2q <= 80 < 82, 8B-aligned
        *(float2*)&sB[r*RSTRIDE + 2*q] = vb;
    }
    __syncthreads();

    float g[K];
    #pragma unroll
    for (int k = 0; k < K; ++k) g[k] = gwS[k];

    // thread -> 4x4 output block: cols cx..cx+3, rows ry..ry+3 (local)
    const int cx = (tid & 15) * 4;
    const int ry = (tid >> 4) * 4;

    float m1[4][4], m2[4][4], e11[4][4], e22[4][4], e12[4][4];
    #pragma unroll
    for (int r = 0; r < 4; ++r)
        #pragma unroll
        for (int c = 0; c < 4; ++c) {
            m1[r][c]=0.f; m2[r][c]=0.f; e11[r][c]=0.f; e22[r][c]=0.f; e12[r][c]=0.f;
        }

    // stream 14 raw rows: rows ry..ry+13; horizontal conv in regs, then
    // scatter-accumulate into the 4 output-row accumulators.
    #pragma unroll
    for (int j = 0; j < 14; ++j) {
        const int rr = ry + j;
        const int base = rr * RSTRIDE + cx;   // word index of window start (even -> 8B aligned)
        float a[20], bb[20];
        #pragma unroll
        for (int u = 0; u < 10; ++u) {
            float2 va = *(const float2*)&sA[base + 2*u];
            float2 vb = *(const float2*)&sB[base + 2*u];
            a[2*u] = va.x;  a[2*u+1] = va.y;
            bb[2*u] = vb.x; bb[2*u+1] = vb.y;
        }
        float h1[4], h2[4], h11[4], h22[4], h12[4];
        #pragma unroll
        for (int c = 0; c < 4; ++c) { h1[c]=0.f; h2[c]=0.f; h11[c]=0.f; h22[c]=0.f; h12[c]=0.f; }

        // output local col c uses window indices i = c+3 .. c+13 (tap k = i-3-c)
        #pragma unroll
        for (int i = 3; i <= 16; ++i) {
            float av = a[i], bv = bb[i];
            float a2 = av*av, b2 = bv*bv, ab = av*bv;
            #pragma unroll
            for (int c = 0; c < 4; ++c) {
                const int k = i - 3 - c;
                if (k >= 0 && k <= 10) {
                    float w = g[k];
                    h1[c]  += w*av;  h2[c]  += w*bv;
                    h11[c] += w*a2;  h22[c] += w*b2;  h12[c] += w*ab;
                }
            }
        }

        // vertical: output row r (local) takes tap k = j - r, valid 0..10
        #pragma unroll
        for (int r = 0; r < 4; ++r) {
            const int k = j - r;
            if (k >= 0 && k <= 10) {
                float w = g[k];
                #pragma unroll
                for (int c = 0; c < 4; ++c) {
                    m1[r][c]  += w*h1[c];  m2[r][c]  += w*h2[c];
                    e11[r][c] += w*h11[c]; e22[r][c] += w*h22[c]; e12[r][c] += w*h12[c];
                }
            }
        }
    }

    // SSIM per pixel + thread accumulate
    const float C1 = 1e-4f, C2 = 9e-4f;
    float acc = 0.f;
    #pragma unroll
    for (int r = 0; r < 4; ++r)
        #pragma unroll
        for (int c = 0; c < 4; ++c) {
            float mu1 = m1[r][c], mu2 = m2[r][c];
            float mu1s = mu1*mu1, mu2s = mu2*mu2, mu12 = mu1*mu2;
            float s1 = e11[r][c] - mu1s, s2 = e22[r][c] - mu2s, s12 = e12[r][c] - mu12;
            float num = (2.f*mu12 + C1) * (2.f*s12 + C2);
            float den = (mu1s + mu2s + C1) * (s1 + s2 + C2);
            acc += num / den;
        }

    // block reduction
    for (int d = 32; d > 0; d >>= 1) acc += __shfl_down(acc, d, 64);
    int wid = tid >> 6, lane = tid & 63;
    if (lane == 0) wred[wid] = acc;
    __syncthreads();
    if (tid == 0) {
        float s = wred[0] + wred[1] + wred[2] + wred[3];
        int bid = (blockIdx.z * gridDim.y + blockIdx.y) * gridDim.x + blockIdx.x;
        partials[bid] = s;
    }
}

__global__ __launch_bounds__(256) void ssim_reduce_kernel(
    const float* __restrict__ partials, int n, float* __restrict__ out)
{
    __shared__ double wsumd[4];
    double s = 0.0;
    for (int i = threadIdx.x; i < n; i += 256) s += (double)partials[i];
    for (int d = 32; d > 0; d >>= 1) s += __shfl_down(s, d, 64);
    int wid = threadIdx.x >> 6, lane = threadIdx.x & 63;
    if (lane == 0) wsumd[wid] = s;
    __syncthreads();
    if (threadIdx.x == 0) {
        double t = wsumd[0] + wsumd[1] + wsumd[2] + wsumd[3];
        out[0] = (float)(t / ((double)BATCH * IMG_H * IMG_W));
    }
}

extern "C" void kernel_launch(void* const* d_in, const int* in_sizes, int n_in,
                              void* d_out, int out_size, void* d_ws, size_t ws_size,
                              hipStream_t stream) {
    const float* img1   = (const float*)d_in[0];
    const float* img2   = (const float*)d_in[1];
    const float* window = (const float*)d_in[2];
    float* out = (float*)d_out;
    float* partials = (float*)d_ws;

    dim3 grid(IMG_W / TILE, IMG_H / TILE, BATCH);   // 8 x 8 x 64 = 4096 blocks
    dim3 block(BSIZE);
    ssim_fused_kernel<<<grid, block, 0, stream>>>(img1, img2, window, partials);

    int npart = (IMG_W / TILE) * (IMG_H / TILE) * BATCH;
    ssim_reduce_kernel<<<1, 256, 0, stream>>>(partials, npart, out);
}